// Round 1
// baseline (885.433 us; speedup 1.0000x reference)
//
#include <hip/hip_runtime.h>
#include <hip/hip_bf16.h>

// RGCN layer: out = relu(x @ W_self^T + b + agg/deg)
//   agg[n] = sum_{e: dst=n} x[src_e] @ W_rel[rel_e]
// Restructured: S[n][r][:] = sum of x[src] over incoming edges of type r,
// then out = relu([S/deg | x] @ [W_rel; W_self^T] + b)  -- single K=1152 GEMM.

#define D 128
#define RNUM 8
#define KREL (RNUM * D)      // 1024
#define KTOT (KREL + D)      // 1152
#define BLK_M 128
#define LDS_PITCH 40         // 32 + 8 pad (keeps 16B alignment, breaks bank aliasing)

typedef short short8 __attribute__((ext_vector_type(8)));
typedef float float4v __attribute__((ext_vector_type(4)));

// fp32 -> bf16 round-nearest-even (bit pattern)
static __device__ __forceinline__ unsigned int f2b(float f) {
    unsigned int u = __float_as_uint(f);
    return (u + 0x7fffu + ((u >> 16) & 1u)) >> 16;
}

// Build B^T (bf16, [128 out][1152 k]): k<1024 -> W_rel[r][d][o], else W_self[o][d]
__global__ void prep_bt_kernel(const float* __restrict__ W_rel,
                               const float* __restrict__ W_self,
                               unsigned short* __restrict__ Bt) {
    int idx = blockIdx.x * 256 + threadIdx.x;
    if (idx >= 128 * KTOT) return;
    int o = idx / KTOT;
    int k = idx - o * KTOT;
    float v;
    if (k < KREL) {
        // W_rel flat [r][d][o] = (r*D+d)*D + o = k*128 + o
        v = W_rel[(size_t)k * D + o];
    } else {
        v = W_self[(size_t)o * D + (k - KREL)];
    }
    Bt[idx] = (unsigned short)f2b(v);
}

// One wave (64 lanes) per edge: S[dst][rel][:] += x[src][:], deg[dst] += 1
__global__ void scatter_kernel(const float* __restrict__ x,
                               const int* __restrict__ ei,
                               const int* __restrict__ et,
                               float* __restrict__ S,
                               float* __restrict__ deg,
                               int E) {
    int wid = blockIdx.x * 4 + (threadIdx.x >> 6);
    if (wid >= E) return;
    int lane = threadIdx.x & 63;
    int src = ei[wid];
    int dst = ei[E + wid];
    int rel = et[wid];
    const float2 xv = *(const float2*)(x + (size_t)src * D + lane * 2);
    float* p = S + ((size_t)dst * KREL + rel * D + lane * 2);
    unsafeAtomicAdd(p, xv.x);
    unsafeAtomicAdd(p + 1, xv.y);
    if (lane == 0) unsafeAtomicAdd(deg + dst, 1.0f);
}

// 128x128 output tile per block, 4 waves (2x2), 16x16x32 bf16 MFMA, K=1152.
// A row n = [S[n]*inv_deg[n] (bf16, staged) | x[n] (bf16, staged)]
__global__ __launch_bounds__(256) void gemm_kernel(
        const float* __restrict__ S,
        const float* __restrict__ x,
        const float* __restrict__ deg,
        const unsigned short* __restrict__ Bt,
        const float* __restrict__ bias,
        float* __restrict__ out,
        int Nn) {
    __shared__ unsigned short As[BLK_M * LDS_PITCH];
    __shared__ unsigned short Bs[128 * LDS_PITCH];

    const int tid  = threadIdx.x;
    const int lane = tid & 63;
    const int w    = tid >> 6;
    const int wm   = w & 1;       // wave row (0..1) -> 64 rows
    const int wn   = w >> 1;      // wave col (0..1) -> 64 cols
    const int l16  = lane & 15;
    const int q    = lane >> 4;   // quad 0..3
    const int row0 = blockIdx.x * BLK_M;

    float4v acc[4][4] = {};

    // A staging: thread -> (row tr + 32p, cols tc..tc+3), 4 fp32 -> 4 bf16
    const int tr = tid >> 3;          // 0..31
    const int tc = (tid & 7) * 4;     // 0..28
    // B staging: thread -> (row tr2 + 64p, cols tc2..tc2+7), 16B of bf16
    const int tr2 = tid >> 2;         // 0..63
    const int tc2 = (tid & 3) * 8;    // 0..24

    // per-thread inv_deg for the 4 rows this thread stages (constant over K)
    float inv[4];
#pragma unroll
    for (int p = 0; p < 4; ++p) {
        int gr = row0 + p * 32 + tr;
        inv[p] = (gr < Nn) ? (1.0f / fmaxf(deg[gr], 1.0f)) : 0.0f;
    }

    for (int kk = 0; kk < KTOT; kk += 32) {
        // ---- stage A tile (128 x 32), fp32 -> bf16, scale S part by inv_deg
#pragma unroll
        for (int p = 0; p < 4; ++p) {
            int r  = p * 32 + tr;
            int gr = row0 + r;
            float4 v = make_float4(0.f, 0.f, 0.f, 0.f);
            if (gr < Nn) {
                if (kk < KREL) {
                    v = *(const float4*)(S + (size_t)gr * KREL + kk + tc);
                    v.x *= inv[p]; v.y *= inv[p]; v.z *= inv[p]; v.w *= inv[p];
                } else {
                    v = *(const float4*)(x + (size_t)gr * D + (kk - KREL) + tc);
                }
            }
            unsigned int p0 = f2b(v.x) | (f2b(v.y) << 16);
            unsigned int p1 = f2b(v.z) | (f2b(v.w) << 16);
            *reinterpret_cast<uint2*>(&As[r * LDS_PITCH + tc]) = make_uint2(p0, p1);
        }
        // ---- stage B tile (128 out-cols x 32 k), already bf16 in Bt
#pragma unroll
        for (int p = 0; p < 2; ++p) {
            int r = p * 64 + tr2;
            *reinterpret_cast<uint4*>(&Bs[r * LDS_PITCH + tc2]) =
                *reinterpret_cast<const uint4*>(&Bt[(size_t)r * KTOT + kk + tc2]);
        }
        __syncthreads();

        short8 a[4], b[4];
#pragma unroll
        for (int mi = 0; mi < 4; ++mi)
            a[mi] = *reinterpret_cast<const short8*>(
                &As[(wm * 64 + mi * 16 + l16) * LDS_PITCH + q * 8]);
#pragma unroll
        for (int ni = 0; ni < 4; ++ni)
            b[ni] = *reinterpret_cast<const short8*>(
                &Bs[(wn * 64 + ni * 16 + l16) * LDS_PITCH + q * 8]);
#pragma unroll
        for (int mi = 0; mi < 4; ++mi)
#pragma unroll
            for (int ni = 0; ni < 4; ++ni)
                acc[mi][ni] = __builtin_amdgcn_mfma_f32_16x16x32_bf16(
                    a[mi], b[ni], acc[mi][ni], 0, 0, 0);
        __syncthreads();
    }

    // ---- epilogue: + bias, relu, store fp32
#pragma unroll
    for (int ni = 0; ni < 4; ++ni) {
        int c = wn * 64 + ni * 16 + l16;
        float bv = bias[c];
#pragma unroll
        for (int mi = 0; mi < 4; ++mi) {
#pragma unroll
            for (int j = 0; j < 4; ++j) {
                int gr = row0 + wm * 64 + mi * 16 + q * 4 + j;
                if (gr < Nn) {
                    float v = acc[mi][ni][j] + bv;
                    out[(size_t)gr * D + c] = fmaxf(v, 0.0f);
                }
            }
        }
    }
}

extern "C" void kernel_launch(void* const* d_in, const int* in_sizes, int n_in,
                              void* d_out, int out_size, void* d_ws, size_t ws_size,
                              hipStream_t stream) {
    const float* x      = (const float*)d_in[0];
    const float* W_rel  = (const float*)d_in[1];
    const float* W_self = (const float*)d_in[2];
    const float* W_bias = (const float*)d_in[3];
    const int*   ei     = (const int*)d_in[4];
    const int*   et     = (const int*)d_in[5];

    const int Nn = in_sizes[0] / D;      // 50000
    const int E  = in_sizes[4] / 2;      // 800000

    // workspace layout: S fp32 [Nn][1024] | deg fp32 [Nn] | Bt bf16 [128][1152]
    size_t s_bytes   = (size_t)Nn * KREL * sizeof(float);
    size_t deg_bytes = ((size_t)Nn * sizeof(float) + 255) & ~(size_t)255;
    float*          S_buf = (float*)d_ws;
    float*          deg   = (float*)((char*)d_ws + s_bytes);
    unsigned short* Bt    = (unsigned short*)((char*)d_ws + s_bytes + deg_bytes);

    // zero S + deg (contiguous)
    hipMemsetAsync(d_ws, 0, s_bytes + deg_bytes, stream);

    prep_bt_kernel<<<(128 * KTOT + 255) / 256, 256, 0, stream>>>(W_rel, W_self, Bt);
    scatter_kernel<<<(E + 3) / 4, 256, 0, stream>>>(x, ei, et, S_buf, deg, E);
    gemm_kernel<<<(Nn + BLK_M - 1) / BLK_M, 256, 0, stream>>>(
        S_buf, x, deg, Bt, W_bias, (float*)d_out, Nn);
}

// Round 2
// 341.129 us; speedup vs baseline: 2.5956x; 2.5956x over previous
//
#include <hip/hip_runtime.h>
#include <hip/hip_bf16.h>

// RGCN layer: out = relu(x @ W_self^T + b + agg/deg)
// Pipeline (atomic-free aggregation):
//   1. counting-sort edges by key = dst*8+rel  (hist -> scan -> reorder src)
//   2. aggregate: one wave per (dst,rel) bin, registers-only sum of x[src],
//      scale by 1/deg(dst), write bf16 into A[dst][rel*128..] ; empty bins
//      write zeros (doubles as the memset). A[n][1024..1151] = bf16(x[n]).
//   3. one K=1152 bf16 MFMA GEMM: out = relu(A @ [W_rel;W_self^T] + b)
//      (m97 pattern: global_load_lds width=16 staging, 64x128 tiles)

#define D 128
#define RNUM 8
#define KREL (RNUM * D)      // 1024
#define KTOT (KREL + D)      // 1152
#define BLK_M 64             // 782 blocks -> ~3/CU, balanced

typedef short short8 __attribute__((ext_vector_type(8)));
typedef float float4v __attribute__((ext_vector_type(4)));

// fp32 -> bf16 round-nearest-even (bit pattern)
static __device__ __forceinline__ unsigned int f2b(float f) {
    unsigned int u = __float_as_uint(f);
    return (u + 0x7fffu + ((u >> 16) & 1u)) >> 16;
}

static __device__ __forceinline__ void gl_lds16(const void* g, void* l) {
    __builtin_amdgcn_global_load_lds(
        (const __attribute__((address_space(1))) unsigned int*)g,
        (__attribute__((address_space(3))) unsigned int*)l, 16, 0, 0);
}

// ---------- B^T prep: bf16 [128 out][1152 k] ----------
__global__ void prep_bt_kernel(const float* __restrict__ W_rel,
                               const float* __restrict__ W_self,
                               unsigned short* __restrict__ Bt) {
    int idx = blockIdx.x * 256 + threadIdx.x;
    if (idx >= 128 * KTOT) return;
    int o = idx / KTOT;
    int k = idx - o * KTOT;
    float v = (k < KREL) ? W_rel[(size_t)k * D + o]          // [r][d][o] flat = k*128+o
                         : W_self[(size_t)o * D + (k - KREL)];
    Bt[idx] = (unsigned short)f2b(v);
}

// ---------- counting sort ----------
__global__ void hist_kernel(const int* __restrict__ ei, const int* __restrict__ et,
                            int* __restrict__ hist, int E) {
    int e = blockIdx.x * 256 + threadIdx.x;
    if (e >= E) return;
    int key = ei[E + e] * RNUM + et[e];
    atomicAdd(hist + key, 1);
}

__global__ void scan1_kernel(const int* __restrict__ hist, int* __restrict__ bsum, int nb) {
    __shared__ int red[256];
    int t = threadIdx.x;
    int base = blockIdx.x * 1024 + t * 4;
    int s = 0;
#pragma unroll
    for (int i = 0; i < 4; ++i) if (base + i < nb) s += hist[base + i];
    red[t] = s;
    __syncthreads();
    for (int off = 128; off > 0; off >>= 1) {
        if (t < off) red[t] += red[t + off];
        __syncthreads();
    }
    if (t == 0) bsum[blockIdx.x] = red[0];
}

__global__ void scan2_kernel(int* __restrict__ bsum, int nparts) {
    __shared__ int tmp[1024];
    int t = threadIdx.x;
    tmp[t] = (t < nparts) ? bsum[t] : 0;
    __syncthreads();
    for (int off = 1; off < 1024; off <<= 1) {
        int v = (t >= off) ? tmp[t - off] : 0;
        __syncthreads();
        tmp[t] += v;
        __syncthreads();
    }
    if (t < nparts) bsum[t] = (t == 0) ? 0 : tmp[t - 1];   // exclusive
}

__global__ void scan3_kernel(const int* __restrict__ hist, const int* __restrict__ bsum,
                             int* __restrict__ offsets, int* __restrict__ cursor, int nb) {
    __shared__ int red[256];
    int t = threadIdx.x;
    int base = blockIdx.x * 1024 + t * 4;
    int v[4]; int s = 0;
#pragma unroll
    for (int i = 0; i < 4; ++i) { v[i] = (base + i < nb) ? hist[base + i] : 0; s += v[i]; }
    red[t] = s;
    __syncthreads();
    for (int off = 1; off < 256; off <<= 1) {       // Hillis-Steele inclusive
        int u = (t >= off) ? red[t - off] : 0;
        __syncthreads();
        red[t] += u;
        __syncthreads();
    }
    int p = bsum[blockIdx.x] + red[t] - s;          // exclusive prefix for this thread
#pragma unroll
    for (int i = 0; i < 4; ++i) {
        if (base + i < nb) { offsets[base + i] = p; cursor[base + i] = p; }
        p += v[i];
    }
}

__global__ void reorder_kernel(const int* __restrict__ ei, const int* __restrict__ et,
                               int* __restrict__ cursor, int* __restrict__ sorted_src, int E) {
    int e = blockIdx.x * 256 + threadIdx.x;
    if (e >= E) return;
    int key = ei[E + e] * RNUM + et[e];
    int pos = atomicAdd(cursor + key, 1);
    sorted_src[pos] = ei[e];
}

// ---------- atomic-free aggregation: wave per (dst,rel) bin ----------
__global__ __launch_bounds__(256) void aggregate_kernel(
        const float* __restrict__ x, const int* __restrict__ offsets,
        const int* __restrict__ sorted_src, unsigned short* __restrict__ A,
        int nb, int E) {
    int wid = blockIdx.x * 4 + (threadIdx.x >> 6);
    if (wid >= nb) return;
    int lane  = threadIdx.x & 63;
    int start = offsets[wid];
    int end   = (wid + 1 < nb) ? offsets[wid + 1] : E;
    int dst = wid >> 3, rel = wid & 7;
    int d0 = offsets[dst << 3];
    int d1 = ((dst << 3) + 8 < nb) ? offsets[(dst << 3) + 8] : E;
    float inv = 1.0f / fmaxf((float)(d1 - d0), 1.0f);
    float ax = 0.f, ay = 0.f;
    for (int e = start; e < end; ++e) {
        int src = sorted_src[e];                      // wave-uniform
        float2 v = *(const float2*)(x + (size_t)src * D + lane * 2);
        ax += v.x; ay += v.y;
    }
    ax *= inv; ay *= inv;
    unsigned int pk = f2b(ax) | (f2b(ay) << 16);
    *(unsigned int*)(A + (size_t)dst * KTOT + rel * D + lane * 2) = pk;
}

// ---------- x -> bf16 into A[:,1024:1152] ----------
__global__ void xcast_kernel(const float* __restrict__ x, unsigned short* __restrict__ A, int Nn) {
    int t = blockIdx.x * 256 + threadIdx.x;
    int n = t >> 5;              // 32 threads/row, 4 cols each
    int c = (t & 31) * 4;
    if (n >= Nn) return;
    float4 v = *(const float4*)(x + (size_t)n * D + c);
    unsigned int p0 = f2b(v.x) | (f2b(v.y) << 16);
    unsigned int p1 = f2b(v.z) | (f2b(v.w) << 16);
    *(uint2*)(A + (size_t)n * KTOT + KREL + c) = make_uint2(p0, p1);
}

// ---------- GEMM: out[64 x 128 tile] = relu(A @ Bt^T + b) ----------
__global__ __launch_bounds__(256) void gemm_kernel(
        const unsigned short* __restrict__ A,
        const unsigned short* __restrict__ Bt,
        const float* __restrict__ bias,
        float* __restrict__ out,
        int Nn) {
    __shared__ unsigned short As[BLK_M * 32];    // 64 rows x 32 k, 64B pitch (no pad: global_load_lds)
    __shared__ unsigned short Bs[128 * 32];

    const int tid  = threadIdx.x;
    const int lane = tid & 63;
    const int w    = tid >> 6;
    const int wm   = w & 1;        // 2 m-slots of 32 rows
    const int wn   = w >> 1;       // 2 n-slots of 64 cols
    const int l16  = lane & 15;
    const int q    = lane >> 4;
    const int row0 = blockIdx.x * BLK_M;

    float4v acc[2][4] = {};

    // staging addresses: lane i -> row chunk (i/4), 16B piece (i%4)
    const int sr = lane >> 2;          // 0..15
    const int sc = (lane & 3) * 8;     // bf16 elems: 0,8,16,24

    for (int kk = 0; kk < KTOT; kk += 32) {
        // A: wave w stages rows w*16 .. w*16+15 (1024B)
        {
            int r = w * 16 + sr;
            const unsigned short* g = A + (size_t)(row0 + r) * KTOT + kk + sc;
            gl_lds16(g, &As[w * 512]);
        }
        // B: wave w stages rows w*32+p*16, p in {0,1}
#pragma unroll
        for (int p = 0; p < 2; ++p) {
            int r = w * 32 + p * 16 + sr;
            const unsigned short* g = Bt + (size_t)r * KTOT + kk + sc;
            gl_lds16(g, &Bs[(w * 2 + p) * 512]);
        }
        __syncthreads();

        short8 a[2], b[4];
#pragma unroll
        for (int mi = 0; mi < 2; ++mi)
            a[mi] = *reinterpret_cast<const short8*>(&As[(wm * 32 + mi * 16 + l16) * 32 + q * 8]);
#pragma unroll
        for (int ni = 0; ni < 4; ++ni)
            b[ni] = *reinterpret_cast<const short8*>(&Bs[(wn * 64 + ni * 16 + l16) * 32 + q * 8]);
#pragma unroll
        for (int mi = 0; mi < 2; ++mi)
#pragma unroll
            for (int ni = 0; ni < 4; ++ni)
                acc[mi][ni] = __builtin_amdgcn_mfma_f32_16x16x32_bf16(a[mi], b[ni], acc[mi][ni], 0, 0, 0);
        __syncthreads();
    }

#pragma unroll
    for (int ni = 0; ni < 4; ++ni) {
        int c = wn * 64 + ni * 16 + l16;
        float bv = bias[c];
#pragma unroll
        for (int mi = 0; mi < 2; ++mi) {
#pragma unroll
            for (int j = 0; j < 4; ++j) {
                int gr = row0 + wm * 32 + mi * 16 + q * 4 + j;
                if (gr < Nn)
                    out[(size_t)gr * D + c] = fmaxf(acc[mi][ni][j] + bv, 0.0f);
            }
        }
    }
}

extern "C" void kernel_launch(void* const* d_in, const int* in_sizes, int n_in,
                              void* d_out, int out_size, void* d_ws, size_t ws_size,
                              hipStream_t stream) {
    const float* x      = (const float*)d_in[0];
    const float* W_rel  = (const float*)d_in[1];
    const float* W_self = (const float*)d_in[2];
    const float* W_bias = (const float*)d_in[3];
    const int*   ei     = (const int*)d_in[4];
    const int*   et     = (const int*)d_in[5];

    const int Nn = in_sizes[0] / D;       // 50000
    const int E  = in_sizes[4] / 2;       // 800000
    const int nb = Nn * RNUM;             // 400000 bins
    const int nparts = (nb + 1023) / 1024;
    const int npad = ((Nn + BLK_M - 1) / BLK_M) * BLK_M;  // pad rows for staging loads

    // ---- workspace layout (256B aligned chunks) ----
    char* p = (char*)d_ws;
    auto take = [&](size_t bytes) { char* q = p; p += (bytes + 255) & ~(size_t)255; return q; };
    unsigned short* A    = (unsigned short*)take((size_t)npad * KTOT * sizeof(unsigned short));
    unsigned short* Bt   = (unsigned short*)take((size_t)128 * KTOT * sizeof(unsigned short));
    int* hist    = (int*)take((size_t)nb * sizeof(int));
    int* offsets = (int*)take((size_t)nb * sizeof(int));
    int* cursor  = (int*)take((size_t)nb * sizeof(int));
    int* bsum    = (int*)take(1024 * sizeof(int));
    int* sorted  = (int*)take((size_t)E * sizeof(int));

    hipMemsetAsync(hist, 0, (size_t)nb * sizeof(int), stream);

    prep_bt_kernel<<<(128 * KTOT + 255) / 256, 256, 0, stream>>>(W_rel, W_self, Bt);
    hist_kernel<<<(E + 255) / 256, 256, 0, stream>>>(ei, et, hist, E);
    scan1_kernel<<<nparts, 256, 0, stream>>>(hist, bsum, nb);
    scan2_kernel<<<1, 1024, 0, stream>>>(bsum, nparts);
    scan3_kernel<<<nparts, 256, 0, stream>>>(hist, bsum, offsets, cursor, nb);
    reorder_kernel<<<(E + 255) / 256, 256, 0, stream>>>(ei, et, cursor, sorted, E);
    aggregate_kernel<<<(nb + 3) / 4, 256, 0, stream>>>(x, offsets, sorted, A, nb, E);
    xcast_kernel<<<(Nn * 32 + 255) / 256, 256, 0, stream>>>(x, A, Nn);
    gemm_kernel<<<npad / BLK_M, 256, 0, stream>>>(A, Bt, W_bias, (float*)d_out, Nn);
}

// Round 3
// 310.745 us; speedup vs baseline: 2.8494x; 1.0978x over previous
//
#include <hip/hip_runtime.h>
#include <hip/hip_bf16.h>

// RGCN layer: out = relu(x @ W_self^T + b + agg/deg)
// Pipeline (atomic-free aggregation, bf16 gathers):
//   0. fused prep: xb = bf16(x) [gather source], A[:,1024:1152] = bf16(x),
//      Bt = bf16([W_rel; W_self^T])  (one kernel, block-range split)
//   1. counting-sort edges by key = dst*8+rel  (hist -> scan -> reorder src)
//   2. aggregate: one wave per (dst,rel) bin, fp32 sum of bf16 xb[src] rows,
//      scale by 1/deg(dst), write bf16 into A[dst][rel*128..]; empty bins
//      write zeros (doubles as the memset).
//   3. one K=1152 bf16 MFMA GEMM: out = relu(A @ Bt^T + b)

#define D 128
#define RNUM 8
#define KREL (RNUM * D)      // 1024
#define KTOT (KREL + D)      // 1152
#define BLK_M 64             // 782 blocks -> ~3/CU, balanced

typedef short short8 __attribute__((ext_vector_type(8)));
typedef float float4v __attribute__((ext_vector_type(4)));

// fp32 -> bf16 round-nearest-even (bit pattern)
static __device__ __forceinline__ unsigned int f2b(float f) {
    unsigned int u = __float_as_uint(f);
    return (u + 0x7fffu + ((u >> 16) & 1u)) >> 16;
}

static __device__ __forceinline__ float b2f_lo(unsigned int u) {
    return __uint_as_float(u << 16);
}
static __device__ __forceinline__ float b2f_hi(unsigned int u) {
    return __uint_as_float(u & 0xffff0000u);
}

static __device__ __forceinline__ void gl_lds16(const void* g, void* l) {
    __builtin_amdgcn_global_load_lds(
        (const __attribute__((address_space(1))) unsigned int*)g,
        (__attribute__((address_space(3))) unsigned int*)l, 16, 0, 0);
}

// ---------- fused prep ----------
// blocks [0, xb_blocks): x -> xb (bf16) and A self columns
// blocks [xb_blocks, ...): Bt build: bf16 [128 out][1152 k]
__global__ void prep_kernel(const float* __restrict__ x,
                            const float* __restrict__ W_rel,
                            const float* __restrict__ W_self,
                            unsigned short* __restrict__ xb,
                            unsigned short* __restrict__ A,
                            unsigned short* __restrict__ Bt,
                            int Nn, int xb_blocks) {
    if (blockIdx.x < (unsigned)xb_blocks) {
        int t = blockIdx.x * 256 + threadIdx.x;
        int n = t >> 5;              // 32 threads/row, 4 cols each
        int c = (t & 31) * 4;
        if (n >= Nn) return;
        float4 v = *(const float4*)(x + (size_t)n * D + c);
        unsigned int p0 = f2b(v.x) | (f2b(v.y) << 16);
        unsigned int p1 = f2b(v.z) | (f2b(v.w) << 16);
        uint2 pk = make_uint2(p0, p1);
        *(uint2*)(xb + (size_t)n * D + c) = pk;
        *(uint2*)(A + (size_t)n * KTOT + KREL + c) = pk;
    } else {
        int idx = (blockIdx.x - xb_blocks) * 256 + threadIdx.x;
        if (idx >= 128 * KTOT) return;
        int o = idx / KTOT;
        int k = idx - o * KTOT;
        float v = (k < KREL) ? W_rel[(size_t)k * D + o]   // [r][d][o] flat = k*128+o
                             : W_self[(size_t)o * D + (k - KREL)];
        Bt[idx] = (unsigned short)f2b(v);
    }
}

// ---------- counting sort ----------
__global__ void hist_kernel(const int* __restrict__ ei, const int* __restrict__ et,
                            int* __restrict__ hist, int E) {
    int e = blockIdx.x * 256 + threadIdx.x;
    if (e >= E) return;
    int key = ei[E + e] * RNUM + et[e];
    atomicAdd(hist + key, 1);
}

__global__ void scan1_kernel(const int* __restrict__ hist, int* __restrict__ bsum, int nb) {
    __shared__ int red[256];
    int t = threadIdx.x;
    int base = blockIdx.x * 1024 + t * 4;
    int s = 0;
#pragma unroll
    for (int i = 0; i < 4; ++i) if (base + i < nb) s += hist[base + i];
    red[t] = s;
    __syncthreads();
    for (int off = 128; off > 0; off >>= 1) {
        if (t < off) red[t] += red[t + off];
        __syncthreads();
    }
    if (t == 0) bsum[blockIdx.x] = red[0];
}

__global__ void scan2_kernel(int* __restrict__ bsum, int nparts) {
    __shared__ int tmp[1024];
    int t = threadIdx.x;
    tmp[t] = (t < nparts) ? bsum[t] : 0;
    __syncthreads();
    for (int off = 1; off < 1024; off <<= 1) {
        int v = (t >= off) ? tmp[t - off] : 0;
        __syncthreads();
        tmp[t] += v;
        __syncthreads();
    }
    if (t < nparts) bsum[t] = (t == 0) ? 0 : tmp[t - 1];   // exclusive
}

__global__ void scan3_kernel(const int* __restrict__ hist, const int* __restrict__ bsum,
                             int* __restrict__ offsets, int* __restrict__ cursor, int nb) {
    __shared__ int red[256];
    int t = threadIdx.x;
    int base = blockIdx.x * 1024 + t * 4;
    int v[4]; int s = 0;
#pragma unroll
    for (int i = 0; i < 4; ++i) { v[i] = (base + i < nb) ? hist[base + i] : 0; s += v[i]; }
    red[t] = s;
    __syncthreads();
    for (int off = 1; off < 256; off <<= 1) {       // Hillis-Steele inclusive
        int u = (t >= off) ? red[t - off] : 0;
        __syncthreads();
        red[t] += u;
        __syncthreads();
    }
    int p = bsum[blockIdx.x] + red[t] - s;          // exclusive prefix for this thread
#pragma unroll
    for (int i = 0; i < 4; ++i) {
        if (base + i < nb) { offsets[base + i] = p; cursor[base + i] = p; }
        p += v[i];
    }
}

__global__ void reorder_kernel(const int* __restrict__ ei, const int* __restrict__ et,
                               int* __restrict__ cursor, int* __restrict__ sorted_src, int E) {
    int e = blockIdx.x * 256 + threadIdx.x;
    if (e >= E) return;
    int key = ei[E + e] * RNUM + et[e];
    int pos = atomicAdd(cursor + key, 1);
    sorted_src[pos] = ei[e];
}

// ---------- atomic-free aggregation: wave per (dst,rel) bin, bf16 gathers ----------
__global__ __launch_bounds__(256) void aggregate_kernel(
        const unsigned short* __restrict__ xb, const int* __restrict__ offsets,
        const int* __restrict__ sorted_src, unsigned short* __restrict__ A,
        int nb, int E) {
    int wid = blockIdx.x * 4 + (threadIdx.x >> 6);
    if (wid >= nb) return;
    int lane  = threadIdx.x & 63;
    int start = offsets[wid];
    int end   = (wid + 1 < nb) ? offsets[wid + 1] : E;
    int dst = wid >> 3, rel = wid & 7;
    int d0 = offsets[dst << 3];
    int d1 = ((dst << 3) + 8 < nb) ? offsets[(dst << 3) + 8] : E;
    float inv = 1.0f / fmaxf((float)(d1 - d0), 1.0f);
    float ax = 0.f, ay = 0.f;
    int e = start;
    // 2-edge unroll: two independent gathers in flight
    for (; e + 1 < end; e += 2) {
        int s0 = sorted_src[e];
        int s1 = sorted_src[e + 1];
        unsigned int u0 = *(const unsigned int*)(xb + (size_t)s0 * D + lane * 2);
        unsigned int u1 = *(const unsigned int*)(xb + (size_t)s1 * D + lane * 2);
        ax += b2f_lo(u0) + b2f_lo(u1);
        ay += b2f_hi(u0) + b2f_hi(u1);
    }
    if (e < end) {
        int s0 = sorted_src[e];
        unsigned int u0 = *(const unsigned int*)(xb + (size_t)s0 * D + lane * 2);
        ax += b2f_lo(u0);
        ay += b2f_hi(u0);
    }
    ax *= inv; ay *= inv;
    unsigned int pk = f2b(ax) | (f2b(ay) << 16);
    *(unsigned int*)(A + (size_t)dst * KTOT + rel * D + lane * 2) = pk;
}

// ---------- GEMM: out[64 x 128 tile] = relu(A @ Bt^T + b) ----------
__global__ __launch_bounds__(256) void gemm_kernel(
        const unsigned short* __restrict__ A,
        const unsigned short* __restrict__ Bt,
        const float* __restrict__ bias,
        float* __restrict__ out,
        int Nn) {
    __shared__ unsigned short As[BLK_M * 32];    // 64 rows x 32 k (no pad: global_load_lds)
    __shared__ unsigned short Bs[128 * 32];

    const int tid  = threadIdx.x;
    const int lane = tid & 63;
    const int w    = tid >> 6;
    const int wm   = w & 1;        // 2 m-slots of 32 rows
    const int wn   = w >> 1;       // 2 n-slots of 64 cols
    const int l16  = lane & 15;
    const int q    = lane >> 4;
    const int row0 = blockIdx.x * BLK_M;

    float4v acc[2][4] = {};

    // staging addresses: lane i -> row chunk (i/4), 16B piece (i%4)
    const int sr = lane >> 2;          // 0..15
    const int sc = (lane & 3) * 8;     // bf16 elems: 0,8,16,24

    for (int kk = 0; kk < KTOT; kk += 32) {
        // A: wave w stages rows w*16 .. w*16+15 (1024B)
        {
            int r = w * 16 + sr;
            const unsigned short* g = A + (size_t)(row0 + r) * KTOT + kk + sc;
            gl_lds16(g, &As[w * 512]);
        }
        // B: wave w stages rows w*32+p*16, p in {0,1}
#pragma unroll
        for (int p = 0; p < 2; ++p) {
            int r = w * 32 + p * 16 + sr;
            const unsigned short* g = Bt + (size_t)r * KTOT + kk + sc;
            gl_lds16(g, &Bs[(w * 2 + p) * 512]);
        }
        __syncthreads();

        short8 a[2], b[4];
#pragma unroll
        for (int mi = 0; mi < 2; ++mi)
            a[mi] = *reinterpret_cast<const short8*>(&As[(wm * 32 + mi * 16 + l16) * 32 + q * 8]);
#pragma unroll
        for (int ni = 0; ni < 4; ++ni)
            b[ni] = *reinterpret_cast<const short8*>(&Bs[(wn * 64 + ni * 16 + l16) * 32 + q * 8]);
#pragma unroll
        for (int mi = 0; mi < 2; ++mi)
#pragma unroll
            for (int ni = 0; ni < 4; ++ni)
                acc[mi][ni] = __builtin_amdgcn_mfma_f32_16x16x32_bf16(a[mi], b[ni], acc[mi][ni], 0, 0, 0);
        __syncthreads();
    }

#pragma unroll
    for (int ni = 0; ni < 4; ++ni) {
        int c = wn * 64 + ni * 16 + l16;
        float bv = bias[c];
#pragma unroll
        for (int mi = 0; mi < 2; ++mi) {
#pragma unroll
            for (int j = 0; j < 4; ++j) {
                int gr = row0 + wm * 32 + mi * 16 + q * 4 + j;
                if (gr < Nn)
                    out[(size_t)gr * D + c] = fmaxf(acc[mi][ni][j] + bv, 0.0f);
            }
        }
    }
}

extern "C" void kernel_launch(void* const* d_in, const int* in_sizes, int n_in,
                              void* d_out, int out_size, void* d_ws, size_t ws_size,
                              hipStream_t stream) {
    const float* x      = (const float*)d_in[0];
    const float* W_rel  = (const float*)d_in[1];
    const float* W_self = (const float*)d_in[2];
    const float* W_bias = (const float*)d_in[3];
    const int*   ei     = (const int*)d_in[4];
    const int*   et     = (const int*)d_in[5];

    const int Nn = in_sizes[0] / D;       // 50000
    const int E  = in_sizes[4] / 2;       // 800000
    const int nb = Nn * RNUM;             // 400000 bins
    const int nparts = (nb + 1023) / 1024;
    const int npad = ((Nn + BLK_M - 1) / BLK_M) * BLK_M;  // pad rows for staging loads

    // ---- workspace layout (256B aligned chunks) ----
    char* p = (char*)d_ws;
    auto take = [&](size_t bytes) { char* q = p; p += (bytes + 255) & ~(size_t)255; return q; };
    unsigned short* A    = (unsigned short*)take((size_t)npad * KTOT * sizeof(unsigned short));
    unsigned short* xb   = (unsigned short*)take((size_t)Nn * D * sizeof(unsigned short));
    unsigned short* Bt   = (unsigned short*)take((size_t)128 * KTOT * sizeof(unsigned short));
    int* hist    = (int*)take((size_t)nb * sizeof(int));
    int* offsets = (int*)take((size_t)nb * sizeof(int));
    int* cursor  = (int*)take((size_t)nb * sizeof(int));
    int* bsum    = (int*)take(1024 * sizeof(int));
    int* sorted  = (int*)take((size_t)E * sizeof(int));

    hipMemsetAsync(hist, 0, (size_t)nb * sizeof(int), stream);

    const int xb_blocks = (Nn * 32 + 255) / 256;
    const int bt_blocks = (128 * KTOT + 255) / 256;
    prep_kernel<<<xb_blocks + bt_blocks, 256, 0, stream>>>(x, W_rel, W_self, xb, A, Bt, Nn, xb_blocks);
    hist_kernel<<<(E + 255) / 256, 256, 0, stream>>>(ei, et, hist, E);
    scan1_kernel<<<nparts, 256, 0, stream>>>(hist, bsum, nb);
    scan2_kernel<<<1, 1024, 0, stream>>>(bsum, nparts);
    scan3_kernel<<<nparts, 256, 0, stream>>>(hist, bsum, offsets, cursor, nb);
    reorder_kernel<<<(E + 255) / 256, 256, 0, stream>>>(ei, et, cursor, sorted, E);
    aggregate_kernel<<<(nb + 3) / 4, 256, 0, stream>>>(xb, offsets, sorted, A, nb, E);
    gemm_kernel<<<npad / BLK_M, 256, 0, stream>>>(A, Bt, W_bias, (float*)d_out, Nn);
}